// Round 6
// baseline (223.859 us; speedup 1.0000x reference)
//
#include <hip/hip_runtime.h>

#define B_    16
#define L_    2048
#define S_    1024
#define DE_   512
#define D_    256
#define NSIL_ 8
#define A_    64
#define MS_   (B_ * S_)   // 16384 sentence rows

// GEMM tile: 64x256, BK=64, 8 waves (2m x 4n), per-wave 32x64 via 16x16x32
#define BM 64
#define BN 256
#define BK 64
#define NGEMM (MS_ / BM)   // 256 gemm blocks (BN == D_: one col block)
#define NT01  128          // t{0,1} blocks, 256 rows each (512 thr)

typedef __attribute__((ext_vector_type(8))) short  short8;
typedef __attribute__((ext_vector_type(4))) float  f32x4;

__device__ __forceinline__ unsigned short f2bf(float f) {
    unsigned int x = __builtin_bit_cast(unsigned int, f);
    x += 0x7fffu + ((x >> 16) & 1u);
    return (unsigned short)(x >> 16);
}
__device__ __forceinline__ float bf2f(unsigned short u) {
    unsigned int x = ((unsigned int)u) << 16;
    return __builtin_bit_cast(float, x);
}

// ---------------------------------------------------------------------------
// Fused: blocks [0,NGEMM) = bf16 MFMA GEMM  Pb = bf16(sent @ w + b), with
// w transposed+converted on the fly during B-staging (kills srse_wt);
// blocks [NGEMM, NGEMM+NT01) = t==0/1 output rows (independent of P).
// ---------------------------------------------------------------------------
__global__ __launch_bounds__(512) void srse_gemm_t01(
    const float*          __restrict__ sent,      // (MS_, DE_) f32
    const float*          __restrict__ w,         // (DE_, D_)  f32 k-major
    const float*          __restrict__ bsh,       // (D_)
    unsigned short*       __restrict__ Pb,        // (MS_, D_)  bf16 out
    const float*          __restrict__ op_emb,    // (VOP, D_)
    const float*          __restrict__ silent,    // (NSIL_, D_)
    const float*          __restrict__ nodes,     // (NN, D_)
    const int*            __restrict__ op_tokens, // (B*L)
    const int*            __restrict__ arg_idx,   // (B*L)
    const int*            __restrict__ item_type, // (B*L)
    const int*            __restrict__ avail,     // (B*L, A_)
    float*                __restrict__ out)       // (B*L, D_)
{
    __shared__ alignas(16) unsigned short As[BM * BK]; // [row][k] swizzled, 8 KB
    __shared__ alignas(16) unsigned short Bs[BN * BK]; // [n][k]   swizzled, 32 KB

    const int t    = threadIdx.x;
    const int lane = t & 63;
    const int wid  = t >> 6;

    if (blockIdx.x < NGEMM) {
        // ---------------- GEMM path ----------------
        const int gm0 = blockIdx.x * BM;
        const int wm  = wid & 1;          // m-half (32 rows)
        const int wn  = wid >> 1;         // n-quarter (64 cols)
        const int fr  = lane & 15;
        const int fq  = lane >> 4;

        f32x4 acc[2][4] = {};

        for (int k0 = 0; k0 < DE_; k0 += BK) {
            // ---- stage A: 64 rows x 64 k (f32 -> bf16), 1 slot/thread ----
            {
                const int row = t >> 3;                  // 0..63
                const int k8  = t & 7;                   // 8-bf16 slot
                const float4 a0 = *(const float4*)(sent + (size_t)(gm0 + row) * DE_ + k0 + k8 * 8);
                const float4 a1 = *(const float4*)(sent + (size_t)(gm0 + row) * DE_ + k0 + k8 * 8 + 4);
                short8 v;
                v[0] = f2bf(a0.x); v[1] = f2bf(a0.y); v[2] = f2bf(a0.z); v[3] = f2bf(a0.w);
                v[4] = f2bf(a1.x); v[5] = f2bf(a1.y); v[6] = f2bf(a1.z); v[7] = f2bf(a1.w);
                *(short8*)(As + ((row * BK + k8 * 8) ^ ((row & 7) << 3))) = v;
            }
            // ---- stage B: transpose w[k][n] -> Bs[n][k] bf16 ----
            // paired-k b32 writes; XOR swizzle makes them bank-conflict-free
            #pragma unroll
            for (int p = 0; p < 4; ++p) {
                const int kk = p * 16 + (t >> 6) * 2;    // even k in [0,64)
                const int n4 = t & 63;                   // 4-col slot
                const float4 b0 = *(const float4*)(w + (size_t)(k0 + kk)     * D_ + n4 * 4);
                const float4 b1 = *(const float4*)(w + (size_t)(k0 + kk + 1) * D_ + n4 * 4);
                const float b0a[4] = {b0.x, b0.y, b0.z, b0.w};
                const float b1a[4] = {b1.x, b1.y, b1.z, b1.w};
                #pragma unroll
                for (int i = 0; i < 4; ++i) {
                    const int n = n4 * 4 + i;
                    const unsigned int v = (unsigned int)f2bf(b0a[i])
                                         | ((unsigned int)f2bf(b1a[i]) << 16);
                    *(unsigned int*)(Bs + ((n * BK + kk) ^ ((n & 7) << 3))) = v;
                }
            }
            __syncthreads();

            #pragma unroll
            for (int ks = 0; ks < 2; ++ks) {
                short8 af[2], bfr[4];
                #pragma unroll
                for (int mf = 0; mf < 2; ++mf) {
                    const int row = wm * 32 + mf * 16 + fr;
                    af[mf] = *(const short8*)(As + ((row * BK + ks * 32 + fq * 8) ^ ((row & 7) << 3)));
                }
                #pragma unroll
                for (int nf = 0; nf < 4; ++nf) {
                    const int n = wn * 64 + nf * 16 + fr;
                    bfr[nf] = *(const short8*)(Bs + ((n * BK + ks * 32 + fq * 8) ^ ((n & 7) << 3)));
                }
                #pragma unroll
                for (int mf = 0; mf < 2; ++mf)
                    #pragma unroll
                    for (int nf = 0; nf < 4; ++nf)
                        acc[mf][nf] = __builtin_amdgcn_mfma_f32_16x16x32_bf16(
                            af[mf], bfr[nf], acc[mf][nf], 0, 0, 0);
            }
            __syncthreads();
        }

        // epilogue: C/D layout col=lane&15, row=(lane>>4)*4+r; store bf16
        #pragma unroll
        for (int nf = 0; nf < 4; ++nf) {
            const int col = wn * 64 + nf * 16 + fr;
            const float bval = bsh[col];
            #pragma unroll
            for (int mf = 0; mf < 2; ++mf) {
                #pragma unroll
                for (int r = 0; r < 4; ++r) {
                    const int row = gm0 + wm * 32 + mf * 16 + fq * 4 + r;
                    Pb[(size_t)row * D_ + col] = f2bf(acc[mf][nf][r] + bval);
                }
            }
        }
    } else {
        // ---------------- t==0 / t==1 rows ----------------
        const int bid2 = blockIdx.x - NGEMM;
        const int r0w  = bid2 * 256 + wid * 32;

        #pragma unroll
        for (int b4 = 0; b4 < 4; ++b4) {
            const int r0 = r0w + b4 * 8;
            const float* src[8];
            int tt8[8];
            #pragma unroll
            for (int i = 0; i < 8; ++i) {
                const int row = r0 + i;
                const int tt  = item_type[row];
                tt8[i] = tt;
                const int a = arg_idx[row];
                int np = a - NSIL_;
                np = np < 0 ? 0 : (np > A_ - 1 ? A_ - 1 : np);
                const float* s0 = op_emb + (size_t)op_tokens[row] * D_;
                const float* s1 = (a < NSIL_)
                                  ? silent + (size_t)a * D_
                                  : nodes + (size_t)avail[(size_t)row * A_ + np] * D_;
                src[i] = (tt == 0) ? s0 : s1;   // t==2: harmless dummy read
            }
            float4 v[8];
            #pragma unroll
            for (int i = 0; i < 8; ++i)
                v[i] = *(const float4*)(src[i] + lane * 4);
            #pragma unroll
            for (int i = 0; i < 8; ++i)
                if (tt8[i] != 2)
                    *(float4*)(out + (size_t)(r0 + i) * D_ + lane * 4) = v[i];
        }
    }
}

// ---------------------------------------------------------------------------
// t==2 rows only: gather bf16 P row, expand to f32, write out.
// ---------------------------------------------------------------------------
__global__ __launch_bounds__(256) void srse_t2(
    const unsigned short* __restrict__ Pb,        // (MS_, D_) bf16
    const int*            __restrict__ shift_idx, // (B*L)
    const int*            __restrict__ item_type, // (B*L)
    float*                __restrict__ out)       // (B*L, D_)
{
    const int wid  = threadIdx.x >> 6;
    const int lane = threadIdx.x & 63;
    const int r0   = blockIdx.x * 64 + wid * 16;

    int tt[16], ss[16];
    #pragma unroll
    for (int i = 0; i < 16; ++i) tt[i] = item_type[r0 + i];
    #pragma unroll
    for (int i = 0; i < 16; ++i) ss[i] = shift_idx[r0 + i];

    #pragma unroll
    for (int i = 0; i < 16; ++i) {
        if (tt[i] == 2) {                          // wave-uniform per row
            const int row = r0 + i;
            const int b   = row >> 11;             // row / L_
            const unsigned short* p = Pb + (size_t)((b << 10) + ss[i]) * D_;
            const short4 x = *(const short4*)(p + lane * 4);   // 8B/lane
            float4 o;
            o.x = bf2f((unsigned short)x.x);
            o.y = bf2f((unsigned short)x.y);
            o.z = bf2f((unsigned short)x.z);
            o.w = bf2f((unsigned short)x.w);
            *(float4*)(out + (size_t)row * D_ + lane * 4) = o;
        }
    }
}

// ---------------------------------------------------------------------------
extern "C" void kernel_launch(void* const* d_in, const int* in_sizes, int n_in,
                              void* d_out, int out_size, void* d_ws, size_t ws_size,
                              hipStream_t stream) {
    const float* sent      = (const float*)d_in[0];
    const float* nodes     = (const float*)d_in[1];
    const float* silent    = (const float*)d_in[2];
    const float* op_emb    = (const float*)d_in[3];
    const float* w         = (const float*)d_in[4];
    const float* bsh       = (const float*)d_in[5];
    const int*   op_tokens = (const int*)d_in[6];
    const int*   arg_idx   = (const int*)d_in[7];
    const int*   shift_idx = (const int*)d_in[8];
    const int*   item_type = (const int*)d_in[9];
    const int*   avail     = (const int*)d_in[10];
    float*       out       = (float*)d_out;

    unsigned short* Pb = (unsigned short*)d_ws;    // 16384 x 256 bf16 = 8 MB

    srse_gemm_t01<<<NGEMM + NT01, 512, 0, stream>>>(
        sent, w, bsh, Pb, op_emb, silent, nodes,
        op_tokens, arg_idx, item_type, avail, out);

    srse_t2<<<(B_ * L_) / 64, 256, 0, stream>>>(Pb, shift_idx, item_type, out);
}

// Round 7
// 218.420 us; speedup vs baseline: 1.0249x; 1.0249x over previous
//
#include <hip/hip_runtime.h>

#define B_    16
#define L_    2048
#define S_    1024
#define DE_   512
#define D_    256
#define NSIL_ 8
#define A_    64
#define MS_   (B_ * S_)   // 16384 sentence rows

// GEMM tile: 64x256, BK=64, 8 waves (2m x 4n), per-wave 32x64 via 16x16x32
#define BM 64
#define BN 256
#define BK 64
#define NGEMM (MS_ / BM)   // 256 gemm blocks (BN == D_: one col block)
#define NT01  128          // t{0,1} blocks, 256 rows each (512 thr)

typedef __attribute__((ext_vector_type(8))) short  short8;
typedef __attribute__((ext_vector_type(4))) float  f32x4;

__device__ __forceinline__ unsigned short f2bf(float f) {
    unsigned int x = __builtin_bit_cast(unsigned int, f);
    x += 0x7fffu + ((x >> 16) & 1u);
    return (unsigned short)(x >> 16);
}
__device__ __forceinline__ float bf2f(unsigned short u) {
    unsigned int x = ((unsigned int)u) << 16;
    return __builtin_bit_cast(float, x);
}

// ---------------------------------------------------------------------------
// LDS-tiled transpose+convert: wT[n][k] = bf16(w[k][n]).
// 32 blocks x 64k x 64n tiles. Coalesced float4 reads, 65-padded LDS
// (column reads 2-way aliased = free), short8 coalesced-ish writes.
// ---------------------------------------------------------------------------
__global__ __launch_bounds__(256) void srse_wt(
    const float* __restrict__ w, unsigned short* __restrict__ wT)
{
    __shared__ float tile[64][65];
    const int t  = threadIdx.x;
    const int kb = (blockIdx.x >> 2) << 6;   // 8 k-blocks
    const int nb = (blockIdx.x & 3) << 6;    // 4 n-blocks

    #pragma unroll
    for (int p = 0; p < 4; ++p) {
        const int id = p * 256 + t;
        const int k  = id >> 4;              // 0..63
        const int n4 = id & 15;              // float4 slot
        const float4 v = *(const float4*)(w + (size_t)(kb + k) * D_ + nb + n4 * 4);
        tile[k][n4 * 4 + 0] = v.x;
        tile[k][n4 * 4 + 1] = v.y;
        tile[k][n4 * 4 + 2] = v.z;
        tile[k][n4 * 4 + 3] = v.w;
    }
    __syncthreads();

    const int n  = t >> 2;                   // 0..63
    const int kq = t & 3;                    // 16-k slot
    short8 o0, o1;
    #pragma unroll
    for (int j = 0; j < 8; ++j) o0[j] = (short)f2bf(tile[kq * 16 + j][n]);
    #pragma unroll
    for (int j = 0; j < 8; ++j) o1[j] = (short)f2bf(tile[kq * 16 + 8 + j][n]);
    *(short8*)(wT + (size_t)(nb + n) * DE_ + kb + kq * 16)     = o0;
    *(short8*)(wT + (size_t)(nb + n) * DE_ + kb + kq * 16 + 8) = o1;
}

// ---------------------------------------------------------------------------
// Fused: blocks [0,NGEMM) = bf16 MFMA GEMM  Pb = bf16(sent @ w + b), B from
// pre-transposed wT (conflict-free staging: each wave's id>>3 mapping spans
// 8 consecutive n -> (n&7)<<3 XOR spreads all 8 bank-quads);
// blocks [NGEMM, NGEMM+NT01) = t==0/1 output rows (independent of P).
// ---------------------------------------------------------------------------
__global__ __launch_bounds__(512) void srse_gemm_t01(
    const float*          __restrict__ sent,      // (MS_, DE_) f32
    const unsigned short* __restrict__ wT,        // (D_, DE_)  bf16
    const float*          __restrict__ bsh,       // (D_)
    unsigned short*       __restrict__ Pb,        // (MS_, D_)  bf16 out
    const float*          __restrict__ op_emb,    // (VOP, D_)
    const float*          __restrict__ silent,    // (NSIL_, D_)
    const float*          __restrict__ nodes,     // (NN, D_)
    const int*            __restrict__ op_tokens, // (B*L)
    const int*            __restrict__ arg_idx,   // (B*L)
    const int*            __restrict__ item_type, // (B*L)
    const int*            __restrict__ avail,     // (B*L, A_)
    float*                __restrict__ out)       // (B*L, D_)
{
    __shared__ alignas(16) unsigned short As[BM * BK]; // [row][k] swizzled, 8 KB
    __shared__ alignas(16) unsigned short Bs[BN * BK]; // [n][k]   swizzled, 32 KB

    const int t    = threadIdx.x;
    const int lane = t & 63;
    const int wid  = t >> 6;

    if (blockIdx.x < NGEMM) {
        // ---------------- GEMM path ----------------
        const int gm0 = blockIdx.x * BM;
        const int wm  = wid & 1;          // m-half (32 rows)
        const int wn  = wid >> 1;         // n-quarter (64 cols)
        const int fr  = lane & 15;
        const int fq  = lane >> 4;

        f32x4 acc[2][4] = {};

        for (int k0 = 0; k0 < DE_; k0 += BK) {
            // ---- stage A: 64 rows x 64 k (f32 -> bf16), 1 slot/thread ----
            {
                const int row = t >> 3;                  // 0..63
                const int k8  = t & 7;                   // 8-bf16 slot
                const float4 a0 = *(const float4*)(sent + (size_t)(gm0 + row) * DE_ + k0 + k8 * 8);
                const float4 a1 = *(const float4*)(sent + (size_t)(gm0 + row) * DE_ + k0 + k8 * 8 + 4);
                short8 v;
                v[0] = f2bf(a0.x); v[1] = f2bf(a0.y); v[2] = f2bf(a0.z); v[3] = f2bf(a0.w);
                v[4] = f2bf(a1.x); v[5] = f2bf(a1.y); v[6] = f2bf(a1.z); v[7] = f2bf(a1.w);
                *(short8*)(As + ((row * BK + k8 * 8) ^ ((row & 7) << 3))) = v;
            }
            // ---- stage B: 256 n x 64 k from wT (bf16 passthrough) ----
            #pragma unroll
            for (int p = 0; p < 4; ++p) {
                const int id = p * 512 + t;
                const int n  = id >> 3;                  // 0..255
                const int k8 = id & 7;
                short8 v = *(const short8*)(wT + (size_t)n * DE_ + k0 + k8 * 8);
                *(short8*)(Bs + ((n * BK + k8 * 8) ^ ((n & 7) << 3))) = v;
            }
            __syncthreads();

            #pragma unroll
            for (int ks = 0; ks < 2; ++ks) {
                short8 af[2], bfr[4];
                #pragma unroll
                for (int mf = 0; mf < 2; ++mf) {
                    const int row = wm * 32 + mf * 16 + fr;
                    af[mf] = *(const short8*)(As + ((row * BK + ks * 32 + fq * 8) ^ ((row & 7) << 3)));
                }
                #pragma unroll
                for (int nf = 0; nf < 4; ++nf) {
                    const int n = wn * 64 + nf * 16 + fr;
                    bfr[nf] = *(const short8*)(Bs + ((n * BK + ks * 32 + fq * 8) ^ ((n & 7) << 3)));
                }
                #pragma unroll
                for (int mf = 0; mf < 2; ++mf)
                    #pragma unroll
                    for (int nf = 0; nf < 4; ++nf)
                        acc[mf][nf] = __builtin_amdgcn_mfma_f32_16x16x32_bf16(
                            af[mf], bfr[nf], acc[mf][nf], 0, 0, 0);
            }
            __syncthreads();
        }

        // epilogue: C/D layout col=lane&15, row=(lane>>4)*4+r; store bf16
        #pragma unroll
        for (int nf = 0; nf < 4; ++nf) {
            const int col = wn * 64 + nf * 16 + fr;
            const float bval = bsh[col];
            #pragma unroll
            for (int mf = 0; mf < 2; ++mf) {
                #pragma unroll
                for (int r = 0; r < 4; ++r) {
                    const int row = gm0 + wm * 32 + mf * 16 + fq * 4 + r;
                    Pb[(size_t)row * D_ + col] = f2bf(acc[mf][nf][r] + bval);
                }
            }
        }
    } else {
        // ---------------- t==0 / t==1 rows ----------------
        const int bid2 = blockIdx.x - NGEMM;
        const int r0w  = bid2 * 256 + wid * 32;

        #pragma unroll
        for (int b4 = 0; b4 < 4; ++b4) {
            const int r0 = r0w + b4 * 8;
            const float* src[8];
            int tt8[8];
            #pragma unroll
            for (int i = 0; i < 8; ++i) {
                const int row = r0 + i;
                const int tt  = item_type[row];
                tt8[i] = tt;
                const int a = arg_idx[row];
                int np = a - NSIL_;
                np = np < 0 ? 0 : (np > A_ - 1 ? A_ - 1 : np);
                const float* s0 = op_emb + (size_t)op_tokens[row] * D_;
                const float* s1 = (a < NSIL_)
                                  ? silent + (size_t)a * D_
                                  : nodes + (size_t)avail[(size_t)row * A_ + np] * D_;
                src[i] = (tt == 0) ? s0 : s1;   // t==2: harmless dummy read
            }
            float4 v[8];
            #pragma unroll
            for (int i = 0; i < 8; ++i)
                v[i] = *(const float4*)(src[i] + lane * 4);
            #pragma unroll
            for (int i = 0; i < 8; ++i)
                if (tt8[i] != 2)
                    *(float4*)(out + (size_t)(r0 + i) * D_ + lane * 4) = v[i];
        }
    }
}

// ---------------------------------------------------------------------------
// t==2 rows only: gather bf16 P row, expand to f32, write out.
// ---------------------------------------------------------------------------
__global__ __launch_bounds__(256) void srse_t2(
    const unsigned short* __restrict__ Pb,        // (MS_, D_) bf16
    const int*            __restrict__ shift_idx, // (B*L)
    const int*            __restrict__ item_type, // (B*L)
    float*                __restrict__ out)       // (B*L, D_)
{
    const int wid  = threadIdx.x >> 6;
    const int lane = threadIdx.x & 63;
    const int r0   = blockIdx.x * 64 + wid * 16;

    int tt[16], ss[16];
    #pragma unroll
    for (int i = 0; i < 16; ++i) tt[i] = item_type[r0 + i];
    #pragma unroll
    for (int i = 0; i < 16; ++i) ss[i] = shift_idx[r0 + i];

    #pragma unroll
    for (int i = 0; i < 16; ++i) {
        if (tt[i] == 2) {                          // wave-uniform per row
            const int row = r0 + i;
            const int b   = row >> 11;             // row / L_
            const unsigned short* p = Pb + (size_t)((b << 10) + ss[i]) * D_;
            const short4 x = *(const short4*)(p + lane * 4);   // 8B/lane
            float4 o;
            o.x = bf2f((unsigned short)x.x);
            o.y = bf2f((unsigned short)x.y);
            o.z = bf2f((unsigned short)x.z);
            o.w = bf2f((unsigned short)x.w);
            *(float4*)(out + (size_t)row * D_ + lane * 4) = o;
        }
    }
}

// ---------------------------------------------------------------------------
extern "C" void kernel_launch(void* const* d_in, const int* in_sizes, int n_in,
                              void* d_out, int out_size, void* d_ws, size_t ws_size,
                              hipStream_t stream) {
    const float* sent      = (const float*)d_in[0];
    const float* nodes     = (const float*)d_in[1];
    const float* silent    = (const float*)d_in[2];
    const float* op_emb    = (const float*)d_in[3];
    const float* w         = (const float*)d_in[4];
    const float* bsh       = (const float*)d_in[5];
    const int*   op_tokens = (const int*)d_in[6];
    const int*   arg_idx   = (const int*)d_in[7];
    const int*   shift_idx = (const int*)d_in[8];
    const int*   item_type = (const int*)d_in[9];
    const int*   avail     = (const int*)d_in[10];
    float*       out       = (float*)d_out;

    unsigned short* wT = (unsigned short*)d_ws;                         // 256 KB
    unsigned short* Pb = (unsigned short*)((char*)d_ws + D_ * DE_ * 2); // 8 MB

    srse_wt<<<32, 256, 0, stream>>>(w, wT);

    srse_gemm_t01<<<NGEMM + NT01, 512, 0, stream>>>(
        sent, wT, bsh, Pb, op_emb, silent, nodes,
        op_tokens, arg_idx, item_type, avail, out);

    srse_t2<<<(B_ * L_) / 64, 256, 0, stream>>>(Pb, shift_idx, item_type, out);
}

// Round 9
// 210.726 us; speedup vs baseline: 1.0623x; 1.0365x over previous
//
#include <hip/hip_runtime.h>

#define B_    16
#define L_    2048
#define S_    1024
#define DE_   512
#define D_    256
#define NSIL_ 8
#define A_    64
#define NR_   (B_ * L_)    // 32768 output rows

// GEMM tile: 64 out-rows x 256 cols, BK=64, 8 waves (2m x 4n)
#define BM 64
#define BN 256
#define BK 64
#define NGEMM (NR_ / BM)   // 512 gemm blocks
#define NT01  256          // t{0,1} gather blocks, 128 rows each

typedef __attribute__((ext_vector_type(8))) short  short8;
typedef __attribute__((ext_vector_type(4))) float  f32x4;

__device__ __forceinline__ unsigned short f2bf(float f) {
    unsigned int x = __builtin_bit_cast(unsigned int, f);
    x += 0x7fffu + ((x >> 16) & 1u);
    return (unsigned short)(x >> 16);
}

// ---------------------------------------------------------------------------
// LDS-tiled transpose+convert: wT[n][k] = bf16(w[k][n]).  (r7, measured OK)
// ---------------------------------------------------------------------------
__global__ __launch_bounds__(256) void srse_wt(
    const float* __restrict__ w, unsigned short* __restrict__ wT)
{
    __shared__ float tile[64][65];
    const int t  = threadIdx.x;
    const int kb = (blockIdx.x >> 2) << 6;   // 8 k-blocks
    const int nb = (blockIdx.x & 3) << 6;    // 4 n-blocks

    #pragma unroll
    for (int p = 0; p < 4; ++p) {
        const int id = p * 256 + t;
        const int k  = id >> 4;
        const int n4 = id & 15;
        const float4 v = *(const float4*)(w + (size_t)(kb + k) * D_ + nb + n4 * 4);
        tile[k][n4 * 4 + 0] = v.x;
        tile[k][n4 * 4 + 1] = v.y;
        tile[k][n4 * 4 + 2] = v.z;
        tile[k][n4 * 4 + 3] = v.w;
    }
    __syncthreads();

    const int n  = t >> 2;
    const int kq = t & 3;
    short8 o0, o1;
    #pragma unroll
    for (int j = 0; j < 8; ++j) o0[j] = (short)f2bf(tile[kq * 16 + j][n]);
    #pragma unroll
    for (int j = 0; j < 8; ++j) o1[j] = (short)f2bf(tile[kq * 16 + 8 + j][n]);
    *(short8*)(wT + (size_t)(nb + n) * DE_ + kb + kq * 16)     = o0;
    *(short8*)(wT + (size_t)(nb + n) * DE_ + kb + kq * 16 + 8) = o1;
}

// ---------------------------------------------------------------------------
// Mega kernel.
// Blocks [0,NGEMM): gathered-A GEMM straight into out for t==2 rows:
//   out[row] = bf16gemm(sent[b(row), shift_idx[row]], w) + b   (predicated)
// Blocks [NGEMM, NGEMM+NT01): t==0/1 gather rows (independent of GEMM).
// ---------------------------------------------------------------------------
__global__ __launch_bounds__(512) void srse_mega(
    const float*          __restrict__ sent,      // (B_*S_, DE_) f32
    const unsigned short* __restrict__ wT,        // (D_, DE_)  bf16
    const float*          __restrict__ bsh,       // (D_)
    const float*          __restrict__ op_emb,    // (VOP, D_)
    const float*          __restrict__ silent,    // (NSIL_, D_)
    const float*          __restrict__ nodes,     // (NN, D_)
    const int*            __restrict__ op_tokens, // (NR_)
    const int*            __restrict__ arg_idx,   // (NR_)
    const int*            __restrict__ shift_idx, // (NR_)
    const int*            __restrict__ item_type, // (NR_)
    const int*            __restrict__ avail,     // (NR_, A_)
    float*                __restrict__ out)       // (NR_, D_)
{
    __shared__ alignas(16) unsigned short As[BM * BK]; // 8 KB, swizzled
    __shared__ alignas(16) unsigned short Bs[BN * BK]; // 32 KB, swizzled

    const int t    = threadIdx.x;
    const int lane = t & 63;
    const int wid  = t >> 6;

    if (blockIdx.x < NGEMM) {
        // ---------------- gathered-A GEMM path ----------------
        const int gm0 = blockIdx.x * BM;

        // per-thread A staging source (fixed across k-loop)
        const int srow = t >> 3;                 // 0..63 local out-row
        const int k8   = t & 7;                  // 8-float slot
        const int orow = gm0 + srow;
        const int sb   = orow >> 11;             // orow / L_
        const float* abase = sent + ((size_t)((sb << 10) + shift_idx[orow]) * DE_) + k8 * 8;
        const int awidx = ((srow * BK + k8 * 8) ^ ((srow & 7) << 3));

        const int wm = wid & 1;                  // m-half (32 rows)
        const int wn = wid >> 1;                 // n-quarter (64 cols)
        const int fr = lane & 15;
        const int fq = lane >> 4;

        f32x4 acc[2][4] = {};

        for (int k0 = 0; k0 < DE_; k0 += BK) {
            // stage A: gathered sent rows, f32 -> bf16
            {
                const float4 a0 = *(const float4*)(abase + k0);
                const float4 a1 = *(const float4*)(abase + k0 + 4);
                short8 v;
                v[0] = f2bf(a0.x); v[1] = f2bf(a0.y); v[2] = f2bf(a0.z); v[3] = f2bf(a0.w);
                v[4] = f2bf(a1.x); v[5] = f2bf(a1.y); v[6] = f2bf(a1.z); v[7] = f2bf(a1.w);
                *(short8*)(As + awidx) = v;
            }
            // stage B: 256 n x 64 k from wT (conflict-free: id>>3 spans 8 n)
            #pragma unroll
            for (int p = 0; p < 4; ++p) {
                const int id = p * 512 + t;
                const int n  = id >> 3;
                const int kb8 = id & 7;
                short8 v = *(const short8*)(wT + (size_t)n * DE_ + k0 + kb8 * 8);
                *(short8*)(Bs + ((n * BK + kb8 * 8) ^ ((n & 7) << 3))) = v;
            }
            __syncthreads();

            #pragma unroll
            for (int ks = 0; ks < 2; ++ks) {
                short8 af[2], bfr[4];
                #pragma unroll
                for (int mf = 0; mf < 2; ++mf) {
                    const int row = wm * 32 + mf * 16 + fr;
                    af[mf] = *(const short8*)(As + ((row * BK + ks * 32 + fq * 8) ^ ((row & 7) << 3)));
                }
                #pragma unroll
                for (int nf = 0; nf < 4; ++nf) {
                    const int n = wn * 64 + nf * 16 + fr;
                    bfr[nf] = *(const short8*)(Bs + ((n * BK + ks * 32 + fq * 8) ^ ((n & 7) << 3)));
                }
                #pragma unroll
                for (int mf = 0; mf < 2; ++mf)
                    #pragma unroll
                    for (int nf = 0; nf < 4; ++nf)
                        acc[mf][nf] = __builtin_amdgcn_mfma_f32_16x16x32_bf16(
                            af[mf], bfr[nf], acc[mf][nf], 0, 0, 0);
            }
            __syncthreads();
        }

        // epilogue: write out ONLY t==2 rows (t01 path owns the rest).
        // C/D layout col=lane&15, row=(lane>>4)*4+r  [m89-verified]
        int t2m[2][4];
        #pragma unroll
        for (int mf = 0; mf < 2; ++mf)
            #pragma unroll
            for (int r = 0; r < 4; ++r)
                t2m[mf][r] = item_type[gm0 + wm * 32 + mf * 16 + fq * 4 + r];

        #pragma unroll
        for (int nf = 0; nf < 4; ++nf) {
            const int col = wn * 64 + nf * 16 + fr;
            const float bval = bsh[col];
            #pragma unroll
            for (int mf = 0; mf < 2; ++mf) {
                #pragma unroll
                for (int r = 0; r < 4; ++r) {
                    if (t2m[mf][r] == 2) {
                        const int row = gm0 + wm * 32 + mf * 16 + fq * 4 + r;
                        out[(size_t)row * D_ + col] = acc[mf][nf][r] + bval;
                    }
                }
            }
        }
    } else {
        // ---------------- t==0 / t==1 rows (16 rows per wave) ----------------
        const int bid2 = blockIdx.x - NGEMM;
        const int r0w  = bid2 * 128 + wid * 16;

        #pragma unroll
        for (int b8 = 0; b8 < 2; ++b8) {
            const int r0 = r0w + b8 * 8;
            const float* src[8];
            int tt8[8];
            #pragma unroll
            for (int i = 0; i < 8; ++i) {
                const int row = r0 + i;
                const int tt  = item_type[row];
                tt8[i] = tt;
                const int a = arg_idx[row];
                int np = a - NSIL_;
                np = np < 0 ? 0 : (np > A_ - 1 ? A_ - 1 : np);
                const float* s0 = op_emb + (size_t)op_tokens[row] * D_;
                const float* s1 = (a < NSIL_)
                                  ? silent + (size_t)a * D_
                                  : nodes + (size_t)avail[(size_t)row * A_ + np] * D_;
                src[i] = (tt == 0) ? s0 : s1;   // t==2: harmless dummy read
            }
            float4 v[8];
            #pragma unroll
            for (int i = 0; i < 8; ++i)
                v[i] = *(const float4*)(src[i] + lane * 4);
            #pragma unroll
            for (int i = 0; i < 8; ++i)
                if (tt8[i] != 2)
                    *(float4*)(out + (size_t)(r0 + i) * D_ + lane * 4) = v[i];
        }
    }
}

// ---------------------------------------------------------------------------
extern "C" void kernel_launch(void* const* d_in, const int* in_sizes, int n_in,
                              void* d_out, int out_size, void* d_ws, size_t ws_size,
                              hipStream_t stream) {
    const float* sent      = (const float*)d_in[0];
    const float* nodes     = (const float*)d_in[1];
    const float* silent    = (const float*)d_in[2];
    const float* op_emb    = (const float*)d_in[3];
    const float* w         = (const float*)d_in[4];
    const float* bsh       = (const float*)d_in[5];
    const int*   op_tokens = (const int*)d_in[6];
    const int*   arg_idx   = (const int*)d_in[7];
    const int*   shift_idx = (const int*)d_in[8];
    const int*   item_type = (const int*)d_in[9];
    const int*   avail     = (const int*)d_in[10];
    float*       out       = (float*)d_out;

    unsigned short* wT = (unsigned short*)d_ws;   // 256 KB bf16 (only ws use)

    srse_wt<<<32, 256, 0, stream>>>(w, wT);

    srse_mega<<<NGEMM + NT01, 512, 0, stream>>>(
        sent, wT, bsh, op_emb, silent, nodes,
        op_tokens, arg_idx, shift_idx, item_type, avail, out);
}

// Round 10
// 207.635 us; speedup vs baseline: 1.0781x; 1.0149x over previous
//
#include <hip/hip_runtime.h>

#define B_    16
#define L_    2048
#define S_    1024
#define DE_   512
#define D_    256
#define NSIL_ 8
#define A_    64
#define NR_   (B_ * L_)    // 32768 output rows

// GEMM tile: 64 worklist-rows x 256 cols, BK=64, 8 waves (2m x 4n)
#define BM 64
#define BN 256
#define BK 64
#define NGEMM (NR_ / BM)   // 512 gemm blocks (worst case; most early-exit)
#define NT01  256          // t{0,1} gather blocks, 128 rows each

#define NPREP_WT 32
#define NPREP_CP (NR_ / 256)   // 128

typedef __attribute__((ext_vector_type(8))) short  short8;
typedef __attribute__((ext_vector_type(4))) float  f32x4;

__device__ __forceinline__ unsigned short f2bf(float f) {
    unsigned int x = __builtin_bit_cast(unsigned int, f);
    x += 0x7fffu + ((x >> 16) & 1u);
    return (unsigned short)(x >> 16);
}

// ---------------------------------------------------------------------------
// Prep: blocks [0,32) = LDS-tiled transpose  wT[n][k] = bf16(w[k][n]);
//       blocks [32,160) = t2-row compaction (wave ballot, 1 atomic/wave).
// ---------------------------------------------------------------------------
__global__ __launch_bounds__(256) void srse_prep(
    const float* __restrict__ w, unsigned short* __restrict__ wT,
    const int* __restrict__ item_type, int* __restrict__ cnt,
    int* __restrict__ wl)
{
    const int t = threadIdx.x;
    if (blockIdx.x < NPREP_WT) {
        __shared__ float tile[64][65];
        const int kb = (blockIdx.x >> 2) << 6;   // 8 k-blocks
        const int nb = (blockIdx.x & 3) << 6;    // 4 n-blocks

        #pragma unroll
        for (int p = 0; p < 4; ++p) {
            const int id = p * 256 + t;
            const int k  = id >> 4;
            const int n4 = id & 15;
            const float4 v = *(const float4*)(w + (size_t)(kb + k) * D_ + nb + n4 * 4);
            tile[k][n4 * 4 + 0] = v.x;
            tile[k][n4 * 4 + 1] = v.y;
            tile[k][n4 * 4 + 2] = v.z;
            tile[k][n4 * 4 + 3] = v.w;
        }
        __syncthreads();

        const int n  = t >> 2;
        const int kq = t & 3;
        short8 o0, o1;
        #pragma unroll
        for (int j = 0; j < 8; ++j) o0[j] = (short)f2bf(tile[kq * 16 + j][n]);
        #pragma unroll
        for (int j = 0; j < 8; ++j) o1[j] = (short)f2bf(tile[kq * 16 + 8 + j][n]);
        *(short8*)(wT + (size_t)(nb + n) * DE_ + kb + kq * 16)     = o0;
        *(short8*)(wT + (size_t)(nb + n) * DE_ + kb + kq * 16 + 8) = o1;
    } else {
        const int row  = (blockIdx.x - NPREP_WT) * 256 + t;
        const int lane = t & 63;
        const bool is2 = (item_type[row] == 2);
        const unsigned long long mask = __ballot(is2);
        int base = 0;
        if (lane == 0 && mask)
            base = atomicAdd(cnt, (int)__popcll(mask));
        base = __shfl(base, 0);
        if (is2)
            wl[base + (int)__popcll(mask & ((1ull << lane) - 1ull))] = row;
    }
}

// ---------------------------------------------------------------------------
// Mega kernel.
// Blocks [0,NGEMM): gathered-A GEMM over COMPACTED t2 rows, straight to out:
//   out[wl[i]] = bf16gemm(sent[b, shift_idx[wl[i]]], w) + b
//   (blocks past ceil(n2/64) early-exit; tail clamps -> benign dup writes)
// Blocks [NGEMM, NGEMM+NT01): t==0/1 gather rows.
// ---------------------------------------------------------------------------
__global__ __launch_bounds__(512) void srse_mega(
    const float*          __restrict__ sent,      // (B_*S_, DE_) f32
    const unsigned short* __restrict__ wT,        // (D_, DE_)  bf16
    const float*          __restrict__ bsh,       // (D_)
    const float*          __restrict__ op_emb,    // (VOP, D_)
    const float*          __restrict__ silent,    // (NSIL_, D_)
    const float*          __restrict__ nodes,     // (NN, D_)
    const int*            __restrict__ op_tokens, // (NR_)
    const int*            __restrict__ arg_idx,   // (NR_)
    const int*            __restrict__ shift_idx, // (NR_)
    const int*            __restrict__ item_type, // (NR_)
    const int*            __restrict__ avail,     // (NR_, A_)
    const int*            __restrict__ cnt,       // t2 count
    const int*            __restrict__ wl,        // t2 worklist
    float*                __restrict__ out)       // (NR_, D_)
{
    __shared__ alignas(16) unsigned short As[BM * BK]; // 8 KB, swizzled
    __shared__ alignas(16) unsigned short Bs[BN * BK]; // 32 KB, swizzled

    const int t    = threadIdx.x;
    const int lane = t & 63;
    const int wid  = t >> 6;

    if (blockIdx.x < NGEMM) {
        // ---------------- compacted gathered-A GEMM ----------------
        const int n2 = *cnt;
        const int i0 = blockIdx.x * BM;
        if (i0 >= n2) return;
        const int m = (n2 - i0 < BM) ? (n2 - i0) : BM;

        // per-thread A staging source (fixed across k-loop)
        const int srow = t >> 3;                 // 0..63 worklist slot
        const int k8   = t & 7;                  // 8-float slot
        const int scl  = (srow < m) ? srow : m - 1;
        const int arow = wl[i0 + scl];
        const int sb   = arow >> 11;             // arow / L_
        const float* abase = sent + ((size_t)((sb << 10) + shift_idx[arow]) * DE_) + k8 * 8;
        const int awidx = ((srow * BK + k8 * 8) ^ ((srow & 7) << 3));

        const int wm = wid & 1;                  // m-half (32 rows)
        const int wn = wid >> 1;                 // n-quarter (64 cols)
        const int fr = lane & 15;
        const int fq = lane >> 4;

        f32x4 acc[2][4] = {};

        for (int k0 = 0; k0 < DE_; k0 += BK) {
            // stage A: gathered sent rows, f32 -> bf16
            {
                const float4 a0 = *(const float4*)(abase + k0);
                const float4 a1 = *(const float4*)(abase + k0 + 4);
                short8 v;
                v[0] = f2bf(a0.x); v[1] = f2bf(a0.y); v[2] = f2bf(a0.z); v[3] = f2bf(a0.w);
                v[4] = f2bf(a1.x); v[5] = f2bf(a1.y); v[6] = f2bf(a1.z); v[7] = f2bf(a1.w);
                *(short8*)(As + awidx) = v;
            }
            // stage B: 256 n x 64 k from wT (conflict-free: id>>3 spans 8 n)
            #pragma unroll
            for (int p = 0; p < 4; ++p) {
                const int id  = p * 512 + t;
                const int n   = id >> 3;
                const int kb8 = id & 7;
                short8 v = *(const short8*)(wT + (size_t)n * DE_ + k0 + kb8 * 8);
                *(short8*)(Bs + ((n * BK + kb8 * 8) ^ ((n & 7) << 3))) = v;
            }
            __syncthreads();

            #pragma unroll
            for (int ks = 0; ks < 2; ++ks) {
                short8 af[2], bfr[4];
                #pragma unroll
                for (int mf = 0; mf < 2; ++mf) {
                    const int row = wm * 32 + mf * 16 + fr;
                    af[mf] = *(const short8*)(As + ((row * BK + ks * 32 + fq * 8) ^ ((row & 7) << 3)));
                }
                #pragma unroll
                for (int nf = 0; nf < 4; ++nf) {
                    const int n = wn * 64 + nf * 16 + fr;
                    bfr[nf] = *(const short8*)(Bs + ((n * BK + ks * 32 + fq * 8) ^ ((n & 7) << 3)));
                }
                #pragma unroll
                for (int mf = 0; mf < 2; ++mf)
                    #pragma unroll
                    for (int nf = 0; nf < 4; ++nf)
                        acc[mf][nf] = __builtin_amdgcn_mfma_f32_16x16x32_bf16(
                            af[mf], bfr[nf], acc[mf][nf], 0, 0, 0);
            }
            __syncthreads();
        }

        // epilogue: all worklist rows are t2 -> unconditional writes.
        // C/D layout col=lane&15, row=(lane>>4)*4+r  [m89-verified]
        int orow[2][4];
        #pragma unroll
        for (int mf = 0; mf < 2; ++mf)
            #pragma unroll
            for (int r = 0; r < 4; ++r) {
                const int lrow = wm * 32 + mf * 16 + fq * 4 + r;
                orow[mf][r] = wl[i0 + ((lrow < m) ? lrow : m - 1)];
            }

        #pragma unroll
        for (int nf = 0; nf < 4; ++nf) {
            const int col = wn * 64 + nf * 16 + fr;
            const float bval = bsh[col];
            #pragma unroll
            for (int mf = 0; mf < 2; ++mf)
                #pragma unroll
                for (int r = 0; r < 4; ++r)
                    out[(size_t)orow[mf][r] * D_ + col] = acc[mf][nf][r] + bval;
        }
    } else {
        // ---------------- t==0 / t==1 rows (16 rows per wave) ----------------
        const int bid2 = blockIdx.x - NGEMM;
        const int r0w  = bid2 * 128 + wid * 16;

        #pragma unroll
        for (int b8 = 0; b8 < 2; ++b8) {
            const int r0 = r0w + b8 * 8;
            const float* src[8];
            int tt8[8];
            #pragma unroll
            for (int i = 0; i < 8; ++i) {
                const int row = r0 + i;
                const int tt  = item_type[row];
                tt8[i] = tt;
                const int a = arg_idx[row];
                int np = a - NSIL_;
                np = np < 0 ? 0 : (np > A_ - 1 ? A_ - 1 : np);
                const float* s0 = op_emb + (size_t)op_tokens[row] * D_;
                const float* s1 = (a < NSIL_)
                                  ? silent + (size_t)a * D_
                                  : nodes + (size_t)avail[(size_t)row * A_ + np] * D_;
                // tt==2 -> cheap L1-resident dummy (op_emb), NOT a random node row
                src[i] = (tt == 1) ? s1 : s0;
            }
            float4 v[8];
            #pragma unroll
            for (int i = 0; i < 8; ++i)
                v[i] = *(const float4*)(src[i] + lane * 4);
            #pragma unroll
            for (int i = 0; i < 8; ++i)
                if (tt8[i] != 2)
                    *(float4*)(out + (size_t)(r0 + i) * D_ + lane * 4) = v[i];
        }
    }
}

// ---------------------------------------------------------------------------
extern "C" void kernel_launch(void* const* d_in, const int* in_sizes, int n_in,
                              void* d_out, int out_size, void* d_ws, size_t ws_size,
                              hipStream_t stream) {
    const float* sent      = (const float*)d_in[0];
    const float* nodes     = (const float*)d_in[1];
    const float* silent    = (const float*)d_in[2];
    const float* op_emb    = (const float*)d_in[3];
    const float* w         = (const float*)d_in[4];
    const float* bsh       = (const float*)d_in[5];
    const int*   op_tokens = (const int*)d_in[6];
    const int*   arg_idx   = (const int*)d_in[7];
    const int*   shift_idx = (const int*)d_in[8];
    const int*   item_type = (const int*)d_in[9];
    const int*   avail     = (const int*)d_in[10];
    float*       out       = (float*)d_out;

    unsigned short* wT  = (unsigned short*)d_ws;                 // 256 KB
    int*            cnt = (int*)((char*)d_ws + 262144);          // 1 int
    int*            wl  = (int*)((char*)d_ws + 262144 + 256);    // 128 KB

    hipMemsetAsync(cnt, 0, sizeof(int), stream);

    srse_prep<<<NPREP_WT + NPREP_CP, 256, 0, stream>>>(w, wT, item_type, cnt, wl);

    srse_mega<<<NGEMM + NT01, 512, 0, stream>>>(
        sent, wT, bsh, op_emb, silent, nodes,
        op_tokens, arg_idx, shift_idx, item_type, avail, cnt, wl, out);
}